// Round 9
// baseline (344.983 us; speedup 1.0000x reference)
//
#include <hip/hip_runtime.h>
#include <hip/hip_bf16.h>

// Ball query: for each (b, p) center, collect first S point indices n with
// ||xyz[b,n] - center[b,p]||^2 < r^2 (index order), zero-fill the rest.
//
// FROZEN FP arithmetic (R6, bit-matches harness "np" ref = XLA w/ contraction):
//   cn = fma(cz,cz, fma(cy,cy, cx*cx))          (contracted mul+reduce)
//   xn = fma(z,z,   fma(y,y,   x*x))
//   dot= fma(cz,z,  fma(cy,y,  cx*x))           (ascending-K FMA)
//   d2 = (cn + xn) - 2*dot ;  valid = d2 < r*r  (all fp32, strict <)
// DO NOT reorder/refactor these ops — a rounding change flips boundary masks.
//
// R9 perf change: persistent waves + dynamic work queue.
// R7/R8 analysis: aggregate VALU work is ~5.5us but kernel ran ~40us because
// long-scanning boundary centers (avg scan ~2600 pts; corner ~7600) drain the
// grid and sit at low occupancy with exposed ~400cyc/iter load->ballot chains
// (OccupancyPercent 27). Fix: launch exactly-resident 2048 blocks (8/CU);
// each wave grabs center indices from a global atomic counter. Occupancy
// stays ~max until the queue empties; tail = one worst center (~5us).
// Inner loop identical to R7 (256-pt batches, 12 loads up front, 4 ballot
// phases, early exit at 256 granularity).

__global__ __launch_bounds__(256) void ball_query_persistent(
    const float* __restrict__ xyz,        // [B, N, 3]
    const float* __restrict__ center,     // [B, P, 3]
    const float* __restrict__ p_radius,   // [1]
    const int*   __restrict__ p_sample,   // [1]
    int* __restrict__ out,                // [B, P, S]
    unsigned* __restrict__ counter,       // [1], zeroed before launch
    int B, int N, int P)
{
    const int S = p_sample[0];
    const float r = p_radius[0];
    const float r2 = __fmul_rn(r, r);

    const int lane = threadIdx.x & 63;
    const int total = B * P;

    while (true) {
        // One wave grabs one center (lane 0 atomics, broadcast to the wave).
        unsigned c = 0;
        if (lane == 0) c = atomicAdd(counter, 1u);
        c = (unsigned)__builtin_amdgcn_readfirstlane((int)c);
        if (c >= (unsigned)total) break;

        const int b = (int)c / P;
        const int p = (int)c - b * P;

        // Center coords + squared norm (same address all lanes -> broadcast)
        const float cx = center[(size_t)c * 3 + 0];
        const float cy = center[(size_t)c * 3 + 1];
        const float cz = center[(size_t)c * 3 + 2];
        // FROZEN: fma-contracted ascending
        const float cn = __builtin_fmaf(cz, cz,
                          __builtin_fmaf(cy, cy, __fmul_rn(cx, cx)));

        const float* xb = xyz + (size_t)b * N * 3;
        int* ob = out + (size_t)c * S;

        int cnt = 0;
        for (int n0 = 0; n0 < N && cnt < S; n0 += 256) {
            // Phase 1: issue all 12 loads (independent -> clustered)
            float px[4], py[4], pz[4];
#pragma unroll
            for (int j = 0; j < 4; ++j) {
                const int n = n0 + j * 64 + lane;
                px[j] = xb[(size_t)n * 3 + 0];
                py[j] = xb[(size_t)n * 3 + 1];
                pz[j] = xb[(size_t)n * 3 + 2];
            }
            // Phase 2: 4 ballot phases in ascending chunk order
#pragma unroll
            for (int j = 0; j < 4; ++j) {
                const float x = px[j], y = py[j], z = pz[j];
                // FROZEN per-point FP sequence:
                const float xn = __builtin_fmaf(z, z,
                                  __builtin_fmaf(y, y, __fmul_rn(x, x)));
                const float dot = __builtin_fmaf(cz, z,
                                   __builtin_fmaf(cy, y, __fmul_rn(cx, x)));
                const float d2 = __fsub_rn(__fadd_rn(cn, xn),
                                           __fmul_rn(2.0f, dot));

                const bool valid = d2 < r2;
                const unsigned long long m = __ballot(valid);
                const int rank = __builtin_amdgcn_mbcnt_hi(
                    (unsigned)(m >> 32),
                    __builtin_amdgcn_mbcnt_lo((unsigned)m, 0u));
                if (valid && (cnt + rank) < S) {
                    ob[cnt + rank] = n0 + j * 64 + lane;
                }
                cnt += __popcll(m);
            }
        }

        // Zero-fill unused slots (harness poisons d_out)
        if (cnt > S) cnt = S;
        for (int s = cnt + lane; s < S; s += 64) {
            ob[s] = 0;
        }
    }
}

extern "C" void kernel_launch(void* const* d_in, const int* in_sizes, int n_in,
                              void* d_out, int out_size, void* d_ws, size_t ws_size,
                              hipStream_t stream) {
    const float* xyz      = (const float*)d_in[0];   // [B, N, 3]
    const float* center   = (const float*)d_in[1];   // [B, P, 3]
    const float* p_radius = (const float*)d_in[2];   // scalar
    const int*   p_sample = (const int*)d_in[3];     // scalar

    const int B = 8;
    const int N = in_sizes[0] / (B * 3);   // 16384
    const int P = in_sizes[1] / (B * 3);   // 2048

    int* out = (int*)d_out;
    unsigned* counter = (unsigned*)d_ws;

    // Zero the work-queue counter (ws is poisoned 0xAA before every launch).
    hipMemsetAsync(counter, 0, sizeof(unsigned), stream);

    // Exactly-resident persistent grid: 256 CUs x 8 blocks (256 thr, low VGPR).
    const int blocks = 2048;
    const int threads = 256;

    ball_query_persistent<<<blocks, threads, 0, stream>>>(
        xyz, center, p_radius, p_sample, out, counter, B, N, P);
}

// Round 11
// 81.616 us; speedup vs baseline: 4.2269x; 4.2269x over previous
//
#include <hip/hip_runtime.h>
#include <hip/hip_bf16.h>

// Ball query: for each (b, p) center, collect first S point indices n with
// ||xyz[b,n] - center[b,p]||^2 < r^2 (index order), zero-fill the rest.
//
// FROZEN FP arithmetic (R6, bit-matches harness "np" ref = XLA w/ contraction):
//   cn = fma(cz,cz, fma(cy,cy, cx*cx))          (contracted mul+reduce)
//   xn = fma(z,z,   fma(y,y,   x*x))
//   dot= fma(cz,z,  fma(cy,y,  cx*x))           (ascending-K FMA)
//   d2 = (cn + xn) - 2*dot ;  valid = d2 < r*r  (all fp32, strict <)
// DO NOT reorder/refactor these ops — a rounding change flips boundary masks.
//
// R11: one block (4 waves) per center, cooperative ordered compaction.
// R10 BUG FIX: loop strode 1024 points/iter but only evaluated 256 (1 point
// per thread) -> 3/4 of points skipped. Now each wave processes 4 chunks per
// iteration (wave w -> points n0 + w*256 + j*64 + lane, j=0..3), so the block
// covers the full 1024. Per iteration: 12 loads up front (R7's proven MLP
// pattern), 4 ballot phases caching mask+popc, lane0 posts the wave total to
// LDS (double-buffered, ONE barrier), prefix over earlier waves + within-wave
// prefix over earlier chunks + mbcnt rank -> exact index order. Straggler
// critical path 64 -> 16 sequential iterations. NO global atomics (R9: 7x
// regression from a single-address atomic queue).

__global__ __launch_bounds__(256) void ball_query_block(
    const float* __restrict__ xyz,        // [B, N, 3]
    const float* __restrict__ center,     // [B, P, 3]
    const float* __restrict__ p_radius,   // [1]
    const int*   __restrict__ p_sample,   // [1]
    int* __restrict__ out,                // [B, P, S]
    int B, int N, int P)
{
    const int S = p_sample[0];
    const float r = p_radius[0];
    const float r2 = __fmul_rn(r, r);

    const int c = blockIdx.x;             // one block per center
    const int lane = threadIdx.x & 63;
    const int wv = threadIdx.x >> 6;      // wave 0..3

    const int b = c / P;

    // Center coords + squared norm (same address all lanes -> broadcast)
    const float cx = center[(size_t)c * 3 + 0];
    const float cy = center[(size_t)c * 3 + 1];
    const float cz = center[(size_t)c * 3 + 2];
    // FROZEN: fma-contracted ascending
    const float cn = __builtin_fmaf(cz, cz,
                      __builtin_fmaf(cy, cy, __fmul_rn(cx, cx)));

    const float* xb = xyz + (size_t)b * N * 3;
    int* ob = out + (size_t)c * S;

    __shared__ int counts[2][4];          // double-buffered per-wave totals

    int cnt = 0;
    int buf = 0;
    // N = 16384 = 16 iterations of 1024; early exit at 1024 granularity.
    for (int n0 = 0; n0 < N; n0 += 1024) {
        const int base = n0 + wv * 256 + lane;   // wave wv -> chunks 4wv..4wv+3

        // Phase 1: issue all 12 loads (independent -> clustered by compiler)
        float px[4], py[4], pz[4];
#pragma unroll
        for (int j = 0; j < 4; ++j) {
            const int n = base + j * 64;
            px[j] = xb[(size_t)n * 3 + 0];
            py[j] = xb[(size_t)n * 3 + 1];
            pz[j] = xb[(size_t)n * 3 + 2];
        }

        // Phase 2: 4 ballot phases, cache masks + per-chunk popcounts
        unsigned long long mm[4];
        int pc[4];
        int wtotal = 0;
#pragma unroll
        for (int j = 0; j < 4; ++j) {
            const float x = px[j], y = py[j], z = pz[j];
            // FROZEN per-point FP sequence:
            const float xn = __builtin_fmaf(z, z,
                              __builtin_fmaf(y, y, __fmul_rn(x, x)));
            const float dot = __builtin_fmaf(cz, z,
                               __builtin_fmaf(cy, y, __fmul_rn(cx, x)));
            const float d2 = __fsub_rn(__fadd_rn(cn, xn), __fmul_rn(2.0f, dot));
            mm[j] = __ballot(d2 < r2);
            pc[j] = __popcll(mm[j]);
            wtotal += pc[j];
        }

        if (lane == 0) counts[buf][wv] = wtotal;
        __syncthreads();

        const int c0 = counts[buf][0];
        const int c1 = counts[buf][1];
        const int c2 = counts[buf][2];
        const int c3 = counts[buf][3];
        int prefix = 0;                   // exclusive prefix over waves < wv
        if (wv > 0) prefix += c0;
        if (wv > 1) prefix += c1;
        if (wv > 2) prefix += c2;
        const int total = (c0 + c1) + (c2 + c3);

        // Phase 3: ordered writes, chunk-by-chunk within the wave
        int off = cnt + prefix;
#pragma unroll
        for (int j = 0; j < 4; ++j) {
            const unsigned long long m = mm[j];
            const bool valid = (m >> lane) & 1ull;
            const int rank = __builtin_amdgcn_mbcnt_hi(
                (unsigned)(m >> 32),
                __builtin_amdgcn_mbcnt_lo((unsigned)m, 0u));
            const int slot = off + rank;
            if (valid && slot < S) {
                ob[slot] = base + j * 64;
            }
            off += pc[j];
        }

        cnt += total;
        buf ^= 1;
        if (cnt >= S) break;              // uniform across block
    }

    // Zero-fill unused slots (harness poisons d_out). Valid writes hit
    // [0, cnt), fills hit [cnt, S) — disjoint, no race.
    if (cnt > S) cnt = S;
    for (int s = cnt + (int)threadIdx.x; s < S; s += 256) {
        ob[s] = 0;
    }
}

extern "C" void kernel_launch(void* const* d_in, const int* in_sizes, int n_in,
                              void* d_out, int out_size, void* d_ws, size_t ws_size,
                              hipStream_t stream) {
    const float* xyz      = (const float*)d_in[0];   // [B, N, 3]
    const float* center   = (const float*)d_in[1];   // [B, P, 3]
    const float* p_radius = (const float*)d_in[2];   // scalar
    const int*   p_sample = (const int*)d_in[3];     // scalar

    const int B = 8;
    const int N = in_sizes[0] / (B * 3);   // 16384
    const int P = in_sizes[1] / (B * 3);   // 2048

    int* out = (int*)d_out;

    // One block (4 waves) per center; consecutive blocks share the same
    // xyz[b] slab -> L1/L2 locality for co-resident blocks.
    const int blocks = B * P;              // 16384
    const int threads = 256;

    ball_query_block<<<blocks, threads, 0, stream>>>(
        xyz, center, p_radius, p_sample, out, B, N, P);
}